// Round 1
// baseline (17.343 us; speedup 1.0000x reference)
//
#include <hip/hip_runtime.h>
#include <math.h>

// Problem constants (from reference setup_inputs):
//   X: (B=32, A=3, S=52, S=52, D=85) f32 ; yboxes: (32,20,4) f32 ;
//   ylabels: (32,20) i32 ; anchors: (3,2) f32 ; nclasses=80
// Reference quirk: wgrid = X.shape[-4] = A = 3 (NOT 52); hgrid = 52.
#define BB    32
#define AA    3
#define SS    52
#define DD    85
#define NN    20
#define NCLS  80
#define KK    (BB * NN)          // 640 boxes
#define WGRID 3
#define HGRID 52
#define HW    (HGRID * WGRID)    // 156 cells
#define BIGV  (1 << 30)

// Kernel 1: zero the output, compute first-claim index per cell.
__global__ void yolo_first_kernel(const float* __restrict__ yboxes,
                                  int* __restrict__ first,
                                  float* __restrict__ out) {
    int tid = threadIdx.x;
    if (tid == 0) out[0] = 0.0f;
    for (int i = tid; i < HW; i += blockDim.x) first[i] = BIGV;
    __syncthreads();
    for (int k = tid; k < KK; k += blockDim.x) {
        float bx = yboxes[4 * k + 0];
        float by = yboxes[4 * k + 1];
        int x = (int)floorf(bx * (float)WGRID);   // in [0,2]
        int y = (int)floorf(by * (float)HGRID);   // in [0,51]
        atomicMin(&first[y * WGRID + x], k);
    }
}

// Kernel 2: one thread per (box k, anchor a) task.
__global__ void yolo_loss_kernel(const float* __restrict__ X,
                                 const float* __restrict__ yboxes,
                                 const int* __restrict__ ylabels,
                                 const float* __restrict__ anchors,
                                 const int* __restrict__ first,
                                 float* __restrict__ out) {
    int t = blockIdx.x * blockDim.x + threadIdx.x;
    float per = 0.0f;
    if (t < KK * AA) {
        int k = t / AA;
        int a = t - k * AA;
        float bx = yboxes[4 * k + 0];
        float by = yboxes[4 * k + 1];
        int x = (int)floorf(bx * (float)WGRID);
        int y = (int)floorf(by * (float)HGRID);
        if (first[y * WGRID + x] == k) {   // only first box per cell contributes
            float bw = yboxes[4 * k + 2];
            float bh = yboxes[4 * k + 3];
            int img = k / NN;
            const float* __restrict__ P =
                X + ((((size_t)img * AA + a) * SS + y) * SS + x) * DD;

            // Gather the 85-float row into registers (constant indices only).
            float p[DD];
#pragma unroll
            for (int d = 0; d < DD; ++d) p[d] = P[d];

            // obj = softplus(-p0), numerically stable (matches jax.nn.softplus)
            float z = -p[0];
            float obj = fmaxf(z, 0.0f) + log1pf(expf(-fabsf(z)));

            // box MSE vs target [xrel, yrel, w/anchor_w, h/anchor_h]
            float xrel = bx * (float)WGRID - (float)x;
            float yrel = by * (float)HGRID - (float)y;
            float wc = bw / anchors[2 * a + 0];
            float hc = bh / anchors[2 * a + 1];
            float d1 = p[1] - xrel, d2 = p[2] - yrel;
            float d3 = p[3] - wc,   d4 = p[4] - hc;
            float boxl = 0.25f * (d1 * d1 + d2 * d2 + d3 * d3 + d4 * d4);

            // class NLL from log_softmax over p[5..84]
            float m = -INFINITY;
#pragma unroll
            for (int c = 0; c < NCLS; ++c) m = fmaxf(m, p[5 + c]);
            float ssum = 0.0f;
#pragma unroll
            for (int c = 0; c < NCLS; ++c) ssum += expf(p[5 + c] - m);
            int lab = ylabels[k];
            // dynamic index: load straight from global (L1-hot) to avoid
            // forcing the p[] register array into scratch (rule #20)
            float plab = P[5 + lab];
            float clsl = -(plab - m - logf(ssum));

            per = 1.0f * obj + 10.0f * boxl + 1.0f * clsl;
        }
    }

    // block reduction: wave shuffle -> LDS -> one atomicAdd per block
    __shared__ float sdata[4];   // 256 threads = 4 waves
    int lane = threadIdx.x & 63;
    int wave = threadIdx.x >> 6;
    float v = per;
#pragma unroll
    for (int off = 32; off > 0; off >>= 1) v += __shfl_down(v, off, 64);
    if (lane == 0) sdata[wave] = v;
    __syncthreads();
    if (wave == 0) {
        float w = (lane < 4) ? sdata[lane] : 0.0f;
#pragma unroll
        for (int off = 32; off > 0; off >>= 1) w += __shfl_down(w, off, 64);
        if (lane == 0) atomicAdd(out, w);
    }
}

extern "C" void kernel_launch(void* const* d_in, const int* in_sizes, int n_in,
                              void* d_out, int out_size, void* d_ws, size_t ws_size,
                              hipStream_t stream) {
    const float* X       = (const float*)d_in[0];
    const float* yboxes  = (const float*)d_in[1];
    const int*   ylabels = (const int*)d_in[2];
    const float* anchors = (const float*)d_in[3];
    // d_in[4] = nclasses scalar (80), hard-coded above.

    float* out  = (float*)d_out;
    int*   first = (int*)d_ws;   // 156 ints, re-initialized every call

    yolo_first_kernel<<<1, 256, 0, stream>>>(yboxes, first, out);

    int tasks  = KK * AA;                     // 1920
    int blocks = (tasks + 255) / 256;         // 8
    yolo_loss_kernel<<<blocks, 256, 0, stream>>>(X, yboxes, ylabels, anchors,
                                                 first, out);
}